// Round 9
// baseline (332.662 us; speedup 1.0000x reference)
//
#include <hip/hip_runtime.h>
#include <hip/hip_bf16.h>

// Problem constants (from reference): L layers, B batch, D width.
constexpr int L = 8;
constexpr int B = 32;
constexpr int D = 1280;

constexpr int JT = 64;              // output columns per block (256B/wave-instr, contiguous)
constexpr int ISPLIT = 4;           // i-reduction split across the block's 4 waves
constexpr int BLOCK = JT * ISPLIT;  // 256 threads
constexpr int ICHUNK = D / ISPLIT;  // 320
constexpr int PF = 16;              // entry W-prefetch depth (regs/thread)

// R1-proven geometry: grid (20,32) = 640 blocks, all co-resident.
// Adds: (1) entry W-prefetch before h-staging (HBM busy from cycle 0);
// (2) tail LLC-prefetch of the NEXT layer's same-tile entry rows -- fills the
// compute-only tail and turns the successor kernel's ramp into LLC hits.
__global__ __launch_bounds__(BLOCK) void layer_kernel(
    const float* __restrict__ h_in,   // [B, D]
    const float* __restrict__ W,      // [B, D, D] this layer
    const float* __restrict__ Wnext,  // [B, D, D] next layer, or nullptr
    const float* __restrict__ bias,   // [B, D]
    const int*   __restrict__ mask,   // [B, D]
    float*       __restrict__ h_out)  // [B, D]
{
    const int b  = blockIdx.y;
    const int j0 = blockIdx.x * JT;
    const int t  = threadIdx.x;
    const int jj = t & (JT - 1);   // 0..63 (lane)
    const int iq = t >> 6;         // 0..3  (wave)
    const int j  = j0 + jj;
    const int i_beg = iq * ICHUNK;

    __shared__ float hs[D];
    __shared__ float partial[BLOCK];

    // (1) entry prefetch: first PF rows of this wave's i-chunk.
    const float* w = W + (size_t)b * D * D + j;
    float pf[PF];
#pragma unroll
    for (int k = 0; k < PF; ++k) pf[k] = w[(size_t)(i_beg + k) * D];

    // Stage h[b,:] into LDS (float4, coalesced; broadcast reads later).
    {
        const float4* src = (const float4*)(h_in + b * D);
        float4* dst = (float4*)hs;
        for (int k = t; k < D / 4; k += BLOCK) dst[k] = src[k];
    }
    __syncthreads();

    // Main i-reduction: consume prefetched regs, then stream W.
    float acc = 0.f;
#pragma unroll
    for (int k = 0; k < PF; ++k) acc = fmaf(hs[i_beg + k], pf[k], acc);
#pragma unroll 16
    for (int i = i_beg + PF; i < i_beg + ICHUNK; ++i)
        acc = fmaf(hs[i], w[(size_t)i * D], acc);

    // (2) tail prefetch: the EXACT addresses the successor block will
    // entry-prefetch next layer (same tile, rows i_beg..i_beg+PF-1).
    // 10MB chip-wide ~ 1.6us of HBM, overlapping the reduce/store tail.
    float sink = 0.f;
    if (Wnext != nullptr) {
        const float* wn = Wnext + (size_t)b * D * D + j;
#pragma unroll
        for (int k = 0; k < PF; ++k) sink += wn[(size_t)(i_beg + k) * D];
    }

    partial[t] = acc;
    __syncthreads();

    if (t < JT) {
        float s = partial[t] + partial[t + 64] + partial[t + 128] + partial[t + 192];
        const int idx = b * D + j0 + t;
        s += bias[idx];
        if (mask[idx]) s = fmaxf(s, 0.f);
        h_out[idx] = s;
    }
    // Keep the prefetch loads live without storing anything (rule 17).
    asm volatile("" :: "v"(sink));
}

extern "C" void kernel_launch(void* const* d_in, const int* in_sizes, int n_in,
                              void* d_out, int out_size, void* d_ws, size_t ws_size,
                              hipStream_t stream) {
    const float* x       = (const float*)d_in[0];  // [B, D]
    const float* weights = (const float*)d_in[1];  // [L, B, D, D]
    const float* biases  = (const float*)d_in[2];  // [L, B, D]
    const int*   masks   = (const int*)  d_in[3];  // [L, B, D]
    float* out = (float*)d_out;                    // [B, D]

    // Ping-pong h through workspace; final layer writes d_out.
    float* ws0 = (float*)d_ws;
    float* ws1 = ws0 + B * D;

    dim3 grid(D / JT, B);
    dim3 block(BLOCK);

    const float* hin = x;
    for (int l = 0; l < L; ++l) {
        float* hout = (l == L - 1) ? out : ((l & 1) ? ws1 : ws0);
        const float* Wl    = weights + (size_t)l * B * D * D;
        const float* Wnext = (l + 1 < L) ? Wl + (size_t)B * D * D : nullptr;
        layer_kernel<<<grid, block, 0, stream>>>(
            hin, Wl, Wnext,
            biases + (size_t)l * B * D,
            masks  + (size_t)l * B * D,
            hout);
        hin = hout;
    }
}